// Round 1
// baseline (651.231 us; speedup 1.0000x reference)
//
#include <hip/hip_runtime.h>
#include <math.h>

#define N_NODES 100000
#define N_EDGES 1250000
#define D 64
#define EPS 1e-8f

// ---------------------------------------------------------------------------
// Kernel 1: hn[i,:] = normalize(tanh(x[i,:] @ W^T + b)), one wave per row.
// W staged in LDS padded to 65 floats/row -> (j+k)%32 bank pattern = 2-way = free.
// x row broadcast via __shfl (no LDS ordering hazards).
// ---------------------------------------------------------------------------
__global__ __launch_bounds__(256) void k_gemm_norm(
    const float* __restrict__ x, const float* __restrict__ W,
    const float* __restrict__ b, float* __restrict__ hn, int nrows)
{
    __shared__ float Wl[D * 65];
    for (int idx = threadIdx.x; idx < D * D; idx += 256) {
        int j = idx >> 6, k = idx & 63;
        Wl[j * 65 + k] = W[idx];
    }
    __syncthreads();

    const int lane = threadIdx.x & 63;
    const int wid  = threadIdx.x >> 6;
    const float bj = b[lane];
    const int wavesTotal = gridDim.x * 4;

    for (int row = blockIdx.x * 4 + wid; row < nrows; row += wavesTotal) {
        float xv = x[row * D + lane];
        float acc = bj;
        #pragma unroll
        for (int k = 0; k < D; ++k) {
            float xk = __shfl(xv, k, 64);
            acc = fmaf(xk, Wl[lane * 65 + k], acc);
        }
        float h = tanhf(acc);
        float s = h * h;
        #pragma unroll
        for (int m = 32; m >= 1; m >>= 1) s += __shfl_xor(s, m, 64);
        float nrm = fmaxf(sqrtf(s), EPS);
        hn[row * D + lane] = h / nrm;
    }
}

// ---------------------------------------------------------------------------
// Kernel 2: deg[i] = 1.0 (self-loop weight)
// ---------------------------------------------------------------------------
__global__ void k_deg_init(float* __restrict__ deg)
{
    int i = blockIdx.x * 256 + threadIdx.x;
    if (i < N_NODES) deg[i] = 1.0f;
}

// ---------------------------------------------------------------------------
// Kernel 3: per-edge cosine similarity (relu'd), plus degree accumulation.
// 16 lanes per edge, float4 loads (64 floats per row).
// ---------------------------------------------------------------------------
__global__ __launch_bounds__(256) void k_edge_w(
    const float* __restrict__ hn, const int* __restrict__ ei,
    float* __restrict__ wout, float* __restrict__ deg)
{
    int t = blockIdx.x * 256 + threadIdx.x;
    int e = t >> 4;
    int sub = t & 15;
    if (e >= N_EDGES) return;
    int s = ei[e];
    int d = ei[N_EDGES + e];
    const float4* ps = (const float4*)(hn + (size_t)s * D);
    const float4* pd = (const float4*)(hn + (size_t)d * D);
    float4 a = ps[sub];
    float4 c = pd[sub];
    float p = a.x * c.x + a.y * c.y + a.z * c.z + a.w * c.w;
    p += __shfl_xor(p, 1, 64);
    p += __shfl_xor(p, 2, 64);
    p += __shfl_xor(p, 4, 64);
    p += __shfl_xor(p, 8, 64);
    if (sub == 0) {
        float w = fmaxf(p, 0.0f);   // relu(cos)
        wout[e] = w;
        atomicAdd(deg + d, w);
    }
}

// ---------------------------------------------------------------------------
// Kernel 4: dis = deg>0 ? rsqrt(max(deg,eps)) : 0 ; f = relu(mask);
//           agg = dis^2 * f  (self-loop term, pre-init for step 0)
// ---------------------------------------------------------------------------
__global__ void k_node_prep(
    const float* __restrict__ deg, const float* __restrict__ mask,
    float* __restrict__ dis, float* __restrict__ f, float* __restrict__ agg)
{
    int i = blockIdx.x * 256 + threadIdx.x;
    if (i >= N_NODES) return;
    float dv = deg[i];
    float di = (dv > 0.0f) ? rsqrtf(fmaxf(dv, EPS)) : 0.0f;
    dis[i] = di;
    float f0 = fmaxf(mask[i], 0.0f);
    f[i] = f0;
    agg[i] = di * di * f0;
}

// ---------------------------------------------------------------------------
// Kernel 5: first scatter, fused with norm_w computation (stored for reuse).
// ---------------------------------------------------------------------------
__global__ void k_scatter0(
    const int* __restrict__ ei, const float* __restrict__ w,
    const float* __restrict__ dis, const float* __restrict__ f,
    float* __restrict__ nw, float* __restrict__ agg)
{
    int e = blockIdx.x * 256 + threadIdx.x;
    if (e >= N_EDGES) return;
    int s = ei[e];
    int d = ei[N_EDGES + e];
    float nwe = dis[s] * w[e] * dis[d];
    nw[e] = nwe;
    atomicAdd(agg + d, nwe * f[s]);
}

// ---------------------------------------------------------------------------
// Kernel 6: subsequent scatters (steps 1..4)
// ---------------------------------------------------------------------------
__global__ void k_scatter(
    const int* __restrict__ ei, const float* __restrict__ nw,
    const float* __restrict__ f, float* __restrict__ agg)
{
    int e = blockIdx.x * 256 + threadIdx.x;
    if (e >= N_EDGES) return;
    int s = ei[e];
    int d = ei[N_EDGES + e];
    atomicAdd(agg + d, nw[e] * f[s]);
}

// ---------------------------------------------------------------------------
// Kernel 7: f = (1-alpha)*agg + alpha*f0 ; re-init agg = dis^2 * f
// ---------------------------------------------------------------------------
__global__ void k_update(
    const float* __restrict__ mask, const float* __restrict__ dis,
    const float* __restrict__ alpha_p, float* __restrict__ f,
    float* __restrict__ agg)
{
    int i = blockIdx.x * 256 + threadIdx.x;
    if (i >= N_NODES) return;
    float alpha = alpha_p[0];
    float f0 = fmaxf(mask[i], 0.0f);
    float fn = (1.0f - alpha) * agg[i] + alpha * f0;
    f[i] = fn;
    float di = dis[i];
    agg[i] = di * di * fn;
}

// ---------------------------------------------------------------------------
// Kernel 8: final step: write f to d_out (no agg re-init needed)
// ---------------------------------------------------------------------------
__global__ void k_final(
    const float* __restrict__ mask, const float* __restrict__ alpha_p,
    const float* __restrict__ agg, float* __restrict__ out)
{
    int i = blockIdx.x * 256 + threadIdx.x;
    if (i >= N_NODES) return;
    float alpha = alpha_p[0];
    float f0 = fmaxf(mask[i], 0.0f);
    out[i] = (1.0f - alpha) * agg[i] + alpha * f0;
}

extern "C" void kernel_launch(void* const* d_in, const int* in_sizes, int n_in,
                              void* d_out, int out_size, void* d_ws, size_t ws_size,
                              hipStream_t stream)
{
    const float* x     = (const float*)d_in[0];   // [N, 64]
    const float* mask  = (const float*)d_in[1];   // [N, 1]
    const int*   ei    = (const int*)  d_in[2];   // [2, E]
    const float* W     = (const float*)d_in[3];   // [64, 64]
    const float* b     = (const float*)d_in[4];   // [64]
    const float* alpha = (const float*)d_in[5];   // [1]

    float* out_f = (float*)d_out;                 // [N]
    float* out_w = (float*)d_out + N_NODES;       // [E]

    // workspace layout (floats)
    float* ws  = (float*)d_ws;
    float* hn  = ws;                    // 6,400,000
    float* nw  = ws + 6400000;          // 1,250,000
    float* deg = ws + 7650000;          //   100,000
    float* dis = ws + 7750000;          //   100,000
    float* f   = ws + 7850000;          //   100,000
    float* agg = ws + 7950000;          //   100,000
    // total 8,050,000 floats = 32.2 MB

    const int nodeBlocks = (N_NODES + 255) / 256;           // 391
    const int edgeBlocks = (N_EDGES + 255) / 256;           // 4883
    const int edgeBlocks16 = (N_EDGES * 16) / 256;          // 78125

    // 1. h = tanh(xW^T + b), normalized rows -> hn
    k_gemm_norm<<<(N_NODES + 3) / 4, 256, 0, stream>>>(x, W, b, hn, N_NODES);
    // 2. deg = 1 (self loops)
    k_deg_init<<<nodeBlocks, 256, 0, stream>>>(deg);
    // 3. edge weights + degree accumulation
    k_edge_w<<<edgeBlocks16, 256, 0, stream>>>(hn, ei, out_w, deg);
    // 4. dis, f0, agg init
    k_node_prep<<<nodeBlocks, 256, 0, stream>>>(deg, mask, dis, f, agg);
    // 5. APPNP step 0 (fused norm_w computation)
    k_scatter0<<<edgeBlocks, 256, 0, stream>>>(ei, out_w, dis, f, nw, agg);
    k_update<<<nodeBlocks, 256, 0, stream>>>(mask, dis, alpha, f, agg);
    // steps 1..3
    for (int t = 1; t <= 3; ++t) {
        k_scatter<<<edgeBlocks, 256, 0, stream>>>(ei, nw, f, agg);
        k_update<<<nodeBlocks, 256, 0, stream>>>(mask, dis, alpha, f, agg);
    }
    // step 4 (final)
    k_scatter<<<edgeBlocks, 256, 0, stream>>>(ei, nw, f, agg);
    k_final<<<nodeBlocks, 256, 0, stream>>>(mask, alpha, agg, out_f);
}

// Round 2
// 555.343 us; speedup vs baseline: 1.1727x; 1.1727x over previous
//
#include <hip/hip_runtime.h>
#include <math.h>

#define N_NODES 100000
#define N_EDGES 1250000
#define D 64
#define EPS 1e-8f

// ---------------------------------------------------------------------------
// Kernel 1: hn[i,:] = normalize(tanh(x[i,:] @ W^T + b))
// Persistent grid. Each lane holds W row `lane` in registers (64 VGPRs).
// Wave's x-row staged in a private LDS slot, read back as broadcast float4
// (same-address across lanes = conflict-free; DS ops in-wave are ordered,
// so no barrier needed).
// ---------------------------------------------------------------------------
__global__ __launch_bounds__(256) void k_gemm_norm(
    const float* __restrict__ x, const float* __restrict__ W,
    const float* __restrict__ b, float* __restrict__ hn)
{
    __shared__ float xrow[4][72];   // per-wave row buffer; 288B slots (16B aligned)
    const int lane = threadIdx.x & 63;
    const int wid  = threadIdx.x >> 6;

    // W row `lane` -> registers (16 float4 loads, L1/L2-hit after first block)
    float Wreg[64];
    const float4* Wv = (const float4*)(W + lane * D);
    #pragma unroll
    for (int q = 0; q < 16; ++q) {
        float4 w4 = Wv[q];
        Wreg[4*q+0] = w4.x; Wreg[4*q+1] = w4.y;
        Wreg[4*q+2] = w4.z; Wreg[4*q+3] = w4.w;
    }
    const float bj = b[lane];
    float* xl = xrow[wid];

    const int wave   = blockIdx.x * 4 + wid;
    const int nwaves = gridDim.x * 4;

    for (int row = wave; row < N_NODES; row += nwaves) {
        float xv = x[(size_t)row * D + lane];   // coalesced 256B per wave
        xl[lane] = xv;
        float acc = bj;
        #pragma unroll
        for (int q = 0; q < 16; ++q) {
            float4 xk4 = *(const float4*)(xl + 4*q);   // broadcast read
            acc = fmaf(xk4.x, Wreg[4*q+0], acc);
            acc = fmaf(xk4.y, Wreg[4*q+1], acc);
            acc = fmaf(xk4.z, Wreg[4*q+2], acc);
            acc = fmaf(xk4.w, Wreg[4*q+3], acc);
        }
        float h = tanhf(acc);
        float s = h * h;
        #pragma unroll
        for (int m = 32; m >= 1; m >>= 1) s += __shfl_xor(s, m, 64);
        float nrm = fmaxf(sqrtf(s), EPS);
        hn[(size_t)row * D + lane] = h / nrm;
    }
}

// ---------------------------------------------------------------------------
// Kernel 2: deg[i] = 1.0 (self-loop weight)
// ---------------------------------------------------------------------------
__global__ void k_deg_init(float* __restrict__ deg)
{
    int i = blockIdx.x * 256 + threadIdx.x;
    if (i < N_NODES) deg[i] = 1.0f;
}

// ---------------------------------------------------------------------------
// Kernel 3: per-edge cosine similarity (relu'd), plus degree accumulation.
// 16 lanes per edge, float4 loads (64 floats per row).
// ---------------------------------------------------------------------------
__global__ __launch_bounds__(256) void k_edge_w(
    const float* __restrict__ hn, const int* __restrict__ ei,
    float* __restrict__ wout, float* __restrict__ deg)
{
    int t = blockIdx.x * 256 + threadIdx.x;
    int e = t >> 4;
    int sub = t & 15;
    if (e >= N_EDGES) return;
    int s = ei[e];
    int d = ei[N_EDGES + e];
    const float4* ps = (const float4*)(hn + (size_t)s * D);
    const float4* pd = (const float4*)(hn + (size_t)d * D);
    float4 a = ps[sub];
    float4 c = pd[sub];
    float p = a.x * c.x + a.y * c.y + a.z * c.z + a.w * c.w;
    p += __shfl_xor(p, 1, 64);
    p += __shfl_xor(p, 2, 64);
    p += __shfl_xor(p, 4, 64);
    p += __shfl_xor(p, 8, 64);
    if (sub == 0) {
        float w = fmaxf(p, 0.0f);   // relu(cos)
        wout[e] = w;
        atomicAdd(deg + d, w);
    }
}

// ---------------------------------------------------------------------------
// Kernel 4: dis = deg>0 ? rsqrt(max(deg,eps)) : 0 ; f = relu(mask);
//           agg = dis^2 * f  (self-loop term, pre-init for step 0)
// ---------------------------------------------------------------------------
__global__ void k_node_prep(
    const float* __restrict__ deg, const float* __restrict__ mask,
    float* __restrict__ dis, float* __restrict__ f, float* __restrict__ agg)
{
    int i = blockIdx.x * 256 + threadIdx.x;
    if (i >= N_NODES) return;
    float dv = deg[i];
    float di = (dv > 0.0f) ? rsqrtf(fmaxf(dv, EPS)) : 0.0f;
    dis[i] = di;
    float f0 = fmaxf(mask[i], 0.0f);
    f[i] = f0;
    agg[i] = di * di * f0;
}

// ---------------------------------------------------------------------------
// Kernel 5: first scatter, fused with norm_w computation (stored for reuse).
// ---------------------------------------------------------------------------
__global__ void k_scatter0(
    const int* __restrict__ ei, const float* __restrict__ w,
    const float* __restrict__ dis, const float* __restrict__ f,
    float* __restrict__ nw, float* __restrict__ agg)
{
    int e = blockIdx.x * 256 + threadIdx.x;
    if (e >= N_EDGES) return;
    int s = ei[e];
    int d = ei[N_EDGES + e];
    float nwe = dis[s] * w[e] * dis[d];
    nw[e] = nwe;
    atomicAdd(agg + d, nwe * f[s]);
}

// ---------------------------------------------------------------------------
// Kernel 6: subsequent scatters (steps 1..4)
// ---------------------------------------------------------------------------
__global__ void k_scatter(
    const int* __restrict__ ei, const float* __restrict__ nw,
    const float* __restrict__ f, float* __restrict__ agg)
{
    int e = blockIdx.x * 256 + threadIdx.x;
    if (e >= N_EDGES) return;
    int s = ei[e];
    int d = ei[N_EDGES + e];
    atomicAdd(agg + d, nw[e] * f[s]);
}

// ---------------------------------------------------------------------------
// Kernel 7: f = (1-alpha)*agg + alpha*f0 ; re-init agg = dis^2 * f
// ---------------------------------------------------------------------------
__global__ void k_update(
    const float* __restrict__ mask, const float* __restrict__ dis,
    const float* __restrict__ alpha_p, float* __restrict__ f,
    float* __restrict__ agg)
{
    int i = blockIdx.x * 256 + threadIdx.x;
    if (i >= N_NODES) return;
    float alpha = alpha_p[0];
    float f0 = fmaxf(mask[i], 0.0f);
    float fn = (1.0f - alpha) * agg[i] + alpha * f0;
    f[i] = fn;
    float di = dis[i];
    agg[i] = di * di * fn;
}

// ---------------------------------------------------------------------------
// Kernel 8: final step: write f to d_out (no agg re-init needed)
// ---------------------------------------------------------------------------
__global__ void k_final(
    const float* __restrict__ mask, const float* __restrict__ alpha_p,
    const float* __restrict__ agg, float* __restrict__ out)
{
    int i = blockIdx.x * 256 + threadIdx.x;
    if (i >= N_NODES) return;
    float alpha = alpha_p[0];
    float f0 = fmaxf(mask[i], 0.0f);
    out[i] = (1.0f - alpha) * agg[i] + alpha * f0;
}

extern "C" void kernel_launch(void* const* d_in, const int* in_sizes, int n_in,
                              void* d_out, int out_size, void* d_ws, size_t ws_size,
                              hipStream_t stream)
{
    const float* x     = (const float*)d_in[0];   // [N, 64]
    const float* mask  = (const float*)d_in[1];   // [N, 1]
    const int*   ei    = (const int*)  d_in[2];   // [2, E]
    const float* W     = (const float*)d_in[3];   // [64, 64]
    const float* b     = (const float*)d_in[4];   // [64]
    const float* alpha = (const float*)d_in[5];   // [1]

    float* out_f = (float*)d_out;                 // [N]
    float* out_w = (float*)d_out + N_NODES;       // [E]

    // workspace layout (floats)
    float* ws  = (float*)d_ws;
    float* hn  = ws;                    // 6,400,000
    float* nw  = ws + 6400000;          // 1,250,000
    float* deg = ws + 7650000;          //   100,000
    float* dis = ws + 7750000;          //   100,000
    float* f   = ws + 7850000;          //   100,000
    float* agg = ws + 7950000;          //   100,000
    // total 8,050,000 floats = 32.2 MB

    const int nodeBlocks = (N_NODES + 255) / 256;           // 391
    const int edgeBlocks = (N_EDGES + 255) / 256;           // 4883
    const int edgeBlocks16 = (N_EDGES * 16) / 256;          // 78125

    // 1. h = tanh(xW^T + b), normalized rows -> hn  (persistent grid)
    k_gemm_norm<<<1024, 256, 0, stream>>>(x, W, b, hn);
    // 2. deg = 1 (self loops)
    k_deg_init<<<nodeBlocks, 256, 0, stream>>>(deg);
    // 3. edge weights + degree accumulation
    k_edge_w<<<edgeBlocks16, 256, 0, stream>>>(hn, ei, out_w, deg);
    // 4. dis, f0, agg init
    k_node_prep<<<nodeBlocks, 256, 0, stream>>>(deg, mask, dis, f, agg);
    // 5. APPNP step 0 (fused norm_w computation)
    k_scatter0<<<edgeBlocks, 256, 0, stream>>>(ei, out_w, dis, f, nw, agg);
    k_update<<<nodeBlocks, 256, 0, stream>>>(mask, dis, alpha, f, agg);
    // steps 1..3
    for (int t = 1; t <= 3; ++t) {
        k_scatter<<<edgeBlocks, 256, 0, stream>>>(ei, nw, f, agg);
        k_update<<<nodeBlocks, 256, 0, stream>>>(mask, dis, alpha, f, agg);
    }
    // step 4 (final)
    k_scatter<<<edgeBlocks, 256, 0, stream>>>(ei, nw, f, agg);
    k_final<<<nodeBlocks, 256, 0, stream>>>(mask, alpha, agg, out_f);
}

// Round 4
// 392.131 us; speedup vs baseline: 1.6607x; 1.4162x over previous
//
#include <hip/hip_runtime.h>
#include <hip/hip_fp16.h>
#include <math.h>

#define N_NODES 100000
#define N_EDGES 1250000
#define D 64
#define EPS 1e-8f

// ---------------------------------------------------------------------------
// Kernel 1: hn[i,:] = normalize(tanh(x[i,:] @ W^T + b)) -> fp16
// Persistent grid; W rows in registers; x row broadcast via LDS float4.
// ---------------------------------------------------------------------------
__global__ __launch_bounds__(256) void k_gemm_norm(
    const float* __restrict__ x, const float* __restrict__ W,
    const float* __restrict__ b, __half* __restrict__ hn)
{
    __shared__ float xrow[4][72];
    const int lane = threadIdx.x & 63;
    const int wid  = threadIdx.x >> 6;

    float Wreg[64];
    const float4* Wv = (const float4*)(W + lane * D);
    #pragma unroll
    for (int q = 0; q < 16; ++q) {
        float4 w4 = Wv[q];
        Wreg[4*q+0] = w4.x; Wreg[4*q+1] = w4.y;
        Wreg[4*q+2] = w4.z; Wreg[4*q+3] = w4.w;
    }
    const float bj = b[lane];
    float* xl = xrow[wid];

    const int wave   = blockIdx.x * 4 + wid;
    const int nwaves = gridDim.x * 4;

    for (int row = wave; row < N_NODES; row += nwaves) {
        float xv = x[(size_t)row * D + lane];
        xl[lane] = xv;
        float acc = bj;
        #pragma unroll
        for (int q = 0; q < 16; ++q) {
            float4 xk4 = *(const float4*)(xl + 4*q);
            acc = fmaf(xk4.x, Wreg[4*q+0], acc);
            acc = fmaf(xk4.y, Wreg[4*q+1], acc);
            acc = fmaf(xk4.z, Wreg[4*q+2], acc);
            acc = fmaf(xk4.w, Wreg[4*q+3], acc);
        }
        float h = tanhf(acc);
        float s = h * h;
        #pragma unroll
        for (int m = 32; m >= 1; m >>= 1) s += __shfl_xor(s, m, 64);
        float nrm = fmaxf(sqrtf(s), EPS);
        hn[(size_t)row * D + lane] = __float2half_rn(h / nrm);
    }
}

// ---------------------------------------------------------------------------
// Kernel 2: deg=1 (self loop), cnt=0
// ---------------------------------------------------------------------------
__global__ void k_init(float* __restrict__ deg, int* __restrict__ cnt)
{
    int i = blockIdx.x * 256 + threadIdx.x;
    if (i < N_NODES) { deg[i] = 1.0f; cnt[i] = 0; }
}

// ---------------------------------------------------------------------------
// Kernel 3: per-edge relu(cos) from fp16 rows; fused deg += w and cnt[d]++.
// 8 lanes per edge, one float4 (= 8 halves) per lane per row.
// ---------------------------------------------------------------------------
__global__ __launch_bounds__(256) void k_edge_w(
    const __half* __restrict__ hn, const int* __restrict__ ei,
    float* __restrict__ wout, float* __restrict__ deg, int* __restrict__ cnt)
{
    long long t = (long long)blockIdx.x * 256 + threadIdx.x;
    int e = (int)(t >> 3);
    int sub = (int)(t & 7);
    if (e >= N_EDGES) return;
    int s = ei[e];
    int d = ei[N_EDGES + e];
    const float4* ps = (const float4*)(hn + (size_t)s * D);
    const float4* pd = (const float4*)(hn + (size_t)d * D);
    float4 a4 = ps[sub];
    float4 c4 = pd[sub];
    const __half2* ah = (const __half2*)&a4;
    const __half2* ch = (const __half2*)&c4;
    float p = 0.0f;
    #pragma unroll
    for (int q = 0; q < 4; ++q) {
        float2 af = __half22float2(ah[q]);
        float2 cf = __half22float2(ch[q]);
        p = fmaf(af.x, cf.x, p);
        p = fmaf(af.y, cf.y, p);
    }
    p += __shfl_xor(p, 1, 64);
    p += __shfl_xor(p, 2, 64);
    p += __shfl_xor(p, 4, 64);
    if (sub == 0) {
        float w = fmaxf(p, 0.0f);
        wout[e] = w;
        atomicAdd(deg + d, w);
        atomicAdd(cnt + d, 1);
    }
}

// ---------------------------------------------------------------------------
// Kernel 4: dis = deg>0 ? rsqrt(max(deg,eps)) : 0 ; f_a = relu(mask)
// ---------------------------------------------------------------------------
__global__ void k_node_prep(
    const float* __restrict__ deg, const float* __restrict__ mask,
    float* __restrict__ dis, float* __restrict__ f)
{
    int i = blockIdx.x * 256 + threadIdx.x;
    if (i >= N_NODES) return;
    float dv = deg[i];
    dis[i] = (dv > 0.0f) ? rsqrtf(fmaxf(dv, EPS)) : 0.0f;
    f[i] = fmaxf(mask[i], 0.0f);
}

// ---------------------------------------------------------------------------
// Scan kernels: exclusive prefix sum of cnt[100000] -> rowptr
// ---------------------------------------------------------------------------
__device__ __forceinline__ int wave_iscan(int v, int lane)
{
    int incl = v;
    #pragma unroll
    for (int m = 1; m < 64; m <<= 1) {
        int o = __shfl_up(incl, m, 64);
        if (lane >= m) incl += o;
    }
    return incl;
}

__global__ __launch_bounds__(256) void k_scan1(
    const int* __restrict__ cnt, int* __restrict__ rowptr, int* __restrict__ bsum)
{
    __shared__ int wsum[4];
    int t = threadIdx.x, b = blockIdx.x;
    int i = b * 256 + t;
    int lane = t & 63, wid = t >> 6;
    int v = (i < N_NODES) ? cnt[i] : 0;
    int incl = wave_iscan(v, lane);
    if (lane == 63) wsum[wid] = incl;
    __syncthreads();
    int off = 0;
    #pragma unroll
    for (int k = 0; k < 4; ++k) if (k < wid) off += wsum[k];
    if (i < N_NODES) rowptr[i] = off + incl - v;   // block-local exclusive
    if (t == 255) bsum[b] = off + incl;            // block total
}

__global__ __launch_bounds__(512) void k_scan2(
    const int* __restrict__ bsum, int* __restrict__ boff, int nblk)
{
    __shared__ int wsum[8];
    int t = threadIdx.x;
    int lane = t & 63, wid = t >> 6;
    int v = (t < nblk) ? bsum[t] : 0;
    int incl = wave_iscan(v, lane);
    if (lane == 63) wsum[wid] = incl;
    __syncthreads();
    int off = 0;
    #pragma unroll
    for (int k = 0; k < 8; ++k) if (k < wid) off += wsum[k];
    if (t < nblk) boff[t] = off + incl - v;        // exclusive
}

__global__ __launch_bounds__(256) void k_scan3(
    int* __restrict__ rowptr, int* __restrict__ rowptr_work,
    const int* __restrict__ boff)
{
    int i = blockIdx.x * 256 + threadIdx.x;
    if (i < N_NODES) {
        int r = rowptr[i] + boff[i >> 8];
        rowptr[i] = r;
        rowptr_work[i] = r;
    }
    if (i == 0) rowptr[N_NODES] = N_EDGES;
}

// ---------------------------------------------------------------------------
// Kernel: CSR placement, fused norm_w = dis[s]*w*dis[d]
// ---------------------------------------------------------------------------
__global__ void k_place(
    const int* __restrict__ ei, const float* __restrict__ w,
    const float* __restrict__ dis, int* __restrict__ rowptr_work,
    int* __restrict__ srcs, float* __restrict__ nwv)
{
    int e = blockIdx.x * 256 + threadIdx.x;
    if (e >= N_EDGES) return;
    int s = ei[e];
    int d = ei[N_EDGES + e];
    float nwe = dis[s] * w[e] * dis[d];
    int pos = atomicAdd(rowptr_work + d, 1);
    srcs[pos] = s;
    nwv[pos] = nwe;
}

// ---------------------------------------------------------------------------
// Kernel: fused APPNP step (gather SpMV + self-loop + update), no atomics.
// f_out[i] = (1-a)*( sum_in + dis[i]^2 * f_in[i] ) + a*relu(mask[i])
// ---------------------------------------------------------------------------
__global__ __launch_bounds__(256) void k_spmv(
    const int* __restrict__ rowptr, const int* __restrict__ srcs,
    const float* __restrict__ nwv, const float* __restrict__ f_in,
    const float* __restrict__ dis, const float* __restrict__ mask,
    const float* __restrict__ alpha_p, float* __restrict__ f_out)
{
    int i = blockIdx.x * 256 + threadIdx.x;
    if (i >= N_NODES) return;
    int beg = rowptr[i], end = rowptr[i + 1];
    float sum = 0.0f;
    int j = beg;
    for (; j + 1 < end; j += 2) {
        float v0 = nwv[j]     * f_in[srcs[j]];
        float v1 = nwv[j + 1] * f_in[srcs[j + 1]];
        sum += v0 + v1;
    }
    if (j < end) sum += nwv[j] * f_in[srcs[j]];
    float di = dis[i];
    float alpha = alpha_p[0];
    float f0 = fmaxf(mask[i], 0.0f);
    f_out[i] = (1.0f - alpha) * (sum + di * di * f_in[i]) + alpha * f0;
}

extern "C" void kernel_launch(void* const* d_in, const int* in_sizes, int n_in,
                              void* d_out, int out_size, void* d_ws, size_t ws_size,
                              hipStream_t stream)
{
    const float* x     = (const float*)d_in[0];
    const float* mask  = (const float*)d_in[1];
    const int*   ei    = (const int*)  d_in[2];
    const float* W     = (const float*)d_in[3];
    const float* b     = (const float*)d_in[4];
    const float* alpha = (const float*)d_in[5];

    float* out_f = (float*)d_out;
    float* out_w = (float*)d_out + N_NODES;

    // workspace layout (float-element offsets)
    float* ws = (float*)d_ws;
    __half* hn        = (__half*)ws;                 // 6.4M halves = 3.2M floats
    int*   srcs       = (int*)  (ws + 3200000);      // 1.25M
    float* nwv        =          ws + 4450000;       // 1.25M
    int*   cnt        = (int*)  (ws + 5700000);      // 100k
    int*   rowptr     = (int*)  (ws + 5800000);      // 100001 (alloc 100016)
    int*   rowptr_wk  = (int*)  (ws + 5900016);      // 100k
    float* deg        =          ws + 6000016;       // 100k
    float* dis        =          ws + 6100016;       // 100k
    float* f_a        =          ws + 6200016;       // 100k
    float* f_b        =          ws + 6300016;       // 100k
    int*   bsum       = (int*)  (ws + 6400016);      // 391 (alloc 512)
    int*   boff       = (int*)  (ws + 6400528);      // 391

    const int nodeBlocks  = (N_NODES + 255) / 256;                 // 391
    const int edgeBlocks  = (N_EDGES + 255) / 256;                 // 4883
    const long long edgeThreads8 = (long long)N_EDGES * 8;
    const int edgeBlocks8 = (int)((edgeThreads8 + 255) / 256);     // 39063 (ceil!)

    k_gemm_norm<<<1024, 256, 0, stream>>>(x, W, b, hn);
    k_init<<<nodeBlocks, 256, 0, stream>>>(deg, cnt);
    k_edge_w<<<edgeBlocks8, 256, 0, stream>>>(hn, ei, out_w, deg, cnt);
    k_node_prep<<<nodeBlocks, 256, 0, stream>>>(deg, mask, dis, f_a);
    k_scan1<<<nodeBlocks, 256, 0, stream>>>(cnt, rowptr, bsum);
    k_scan2<<<1, 512, 0, stream>>>(bsum, boff, nodeBlocks);
    k_scan3<<<nodeBlocks, 256, 0, stream>>>(rowptr, rowptr_wk, boff);
    k_place<<<edgeBlocks, 256, 0, stream>>>(ei, out_w, dis, rowptr_wk, srcs, nwv);

    // 5 APPNP steps, ping-pong f_a/f_b, last writes d_out
    k_spmv<<<nodeBlocks, 256, 0, stream>>>(rowptr, srcs, nwv, f_a, dis, mask, alpha, f_b);
    k_spmv<<<nodeBlocks, 256, 0, stream>>>(rowptr, srcs, nwv, f_b, dis, mask, alpha, f_a);
    k_spmv<<<nodeBlocks, 256, 0, stream>>>(rowptr, srcs, nwv, f_a, dis, mask, alpha, f_b);
    k_spmv<<<nodeBlocks, 256, 0, stream>>>(rowptr, srcs, nwv, f_b, dis, mask, alpha, f_a);
    k_spmv<<<nodeBlocks, 256, 0, stream>>>(rowptr, srcs, nwv, f_a, dis, mask, alpha, out_f);
}

// Round 5
// 283.691 us; speedup vs baseline: 2.2956x; 1.3822x over previous
//
#include <hip/hip_runtime.h>
#include <hip/hip_fp16.h>
#include <math.h>

#define N_NODES 100000
#define N_EDGES 1250000
#define D 64
#define EPS 1e-8f

// ---------------------------------------------------------------------------
// Kernel 1: hn[i,:] = normalize(tanh(x[i,:] @ W^T + b)) -> fp16
// Persistent grid; W rows in registers; x row broadcast via LDS float4.
// ---------------------------------------------------------------------------
__global__ __launch_bounds__(256) void k_gemm_norm(
    const float* __restrict__ x, const float* __restrict__ W,
    const float* __restrict__ b, __half* __restrict__ hn)
{
    __shared__ float xrow[4][72];
    const int lane = threadIdx.x & 63;
    const int wid  = threadIdx.x >> 6;

    float Wreg[64];
    const float4* Wv = (const float4*)(W + lane * D);
    #pragma unroll
    for (int q = 0; q < 16; ++q) {
        float4 w4 = Wv[q];
        Wreg[4*q+0] = w4.x; Wreg[4*q+1] = w4.y;
        Wreg[4*q+2] = w4.z; Wreg[4*q+3] = w4.w;
    }
    const float bj = b[lane];
    float* xl = xrow[wid];

    const int wave   = blockIdx.x * 4 + wid;
    const int nwaves = gridDim.x * 4;

    for (int row = wave; row < N_NODES; row += nwaves) {
        float xv = x[(size_t)row * D + lane];
        xl[lane] = xv;
        float acc = bj;
        #pragma unroll
        for (int q = 0; q < 16; ++q) {
            float4 xk4 = *(const float4*)(xl + 4*q);
            acc = fmaf(xk4.x, Wreg[4*q+0], acc);
            acc = fmaf(xk4.y, Wreg[4*q+1], acc);
            acc = fmaf(xk4.z, Wreg[4*q+2], acc);
            acc = fmaf(xk4.w, Wreg[4*q+3], acc);
        }
        float h = tanhf(acc);
        float s = h * h;
        #pragma unroll
        for (int m = 32; m >= 1; m >>= 1) s += __shfl_xor(s, m, 64);
        float nrm = fmaxf(sqrtf(s), EPS);
        hn[(size_t)row * D + lane] = __float2half_rn(h / nrm);
    }
}

// ---------------------------------------------------------------------------
// cnt = 0
// ---------------------------------------------------------------------------
__global__ void k_zero(int* __restrict__ cnt)
{
    int i = blockIdx.x * 256 + threadIdx.x;
    if (i < N_NODES) cnt[i] = 0;
}

// ---------------------------------------------------------------------------
// The ONLY atomic pass: per-edge rank within its destination node.
// ---------------------------------------------------------------------------
__global__ void k_rank(const int* __restrict__ ei, int* __restrict__ cnt,
                       int* __restrict__ rank)
{
    int e = blockIdx.x * 256 + threadIdx.x;
    if (e >= N_EDGES) return;
    int d = ei[N_EDGES + e];
    rank[e] = atomicAdd(cnt + d, 1);
}

// ---------------------------------------------------------------------------
// Scan kernels: exclusive prefix sum of cnt[100000] -> rowptr
// ---------------------------------------------------------------------------
__device__ __forceinline__ int wave_iscan(int v, int lane)
{
    int incl = v;
    #pragma unroll
    for (int m = 1; m < 64; m <<= 1) {
        int o = __shfl_up(incl, m, 64);
        if (lane >= m) incl += o;
    }
    return incl;
}

__global__ __launch_bounds__(256) void k_scan1(
    const int* __restrict__ cnt, int* __restrict__ rowptr, int* __restrict__ bsum)
{
    __shared__ int wsum[4];
    int t = threadIdx.x, b = blockIdx.x;
    int i = b * 256 + t;
    int lane = t & 63, wid = t >> 6;
    int v = (i < N_NODES) ? cnt[i] : 0;
    int incl = wave_iscan(v, lane);
    if (lane == 63) wsum[wid] = incl;
    __syncthreads();
    int off = 0;
    #pragma unroll
    for (int k = 0; k < 4; ++k) if (k < wid) off += wsum[k];
    if (i < N_NODES) rowptr[i] = off + incl - v;   // block-local exclusive
    if (t == 255) bsum[b] = off + incl;            // block total
}

__global__ __launch_bounds__(512) void k_scan2(
    const int* __restrict__ bsum, int* __restrict__ boff, int nblk)
{
    __shared__ int wsum[8];
    int t = threadIdx.x;
    int lane = t & 63, wid = t >> 6;
    int v = (t < nblk) ? bsum[t] : 0;
    int incl = wave_iscan(v, lane);
    if (lane == 63) wsum[wid] = incl;
    __syncthreads();
    int off = 0;
    #pragma unroll
    for (int k = 0; k < 8; ++k) if (k < wid) off += wsum[k];
    if (t < nblk) boff[t] = off + incl - v;        // exclusive
}

__global__ __launch_bounds__(256) void k_scan3(
    int* __restrict__ rowptr, const int* __restrict__ boff)
{
    int i = blockIdx.x * 256 + threadIdx.x;
    if (i < N_NODES) rowptr[i] += boff[i >> 8];
    if (i == 0) rowptr[N_NODES] = N_EDGES;
}

// ---------------------------------------------------------------------------
// Fused cosine + CSR placement. ZERO atomics. 8 lanes/edge, 2 edges/thread
// (4 gathers in flight per lane). pairs[pos] = {src, w} packed 8B store.
// ---------------------------------------------------------------------------
__device__ __forceinline__ float dot8h(float4 a, float4 c)
{
    const __half2* ah = (const __half2*)&a;
    const __half2* ch = (const __half2*)&c;
    float p = 0.0f;
    #pragma unroll
    for (int q = 0; q < 4; ++q) {
        float2 af = __half22float2(ah[q]);
        float2 cf = __half22float2(ch[q]);
        p = fmaf(af.x, cf.x, p);
        p = fmaf(af.y, cf.y, p);
    }
    return p;
}

__global__ __launch_bounds__(256) void k_edge_place(
    const __half* __restrict__ hn, const int* __restrict__ ei,
    const int* __restrict__ rank, const int* __restrict__ rowptr,
    float* __restrict__ wout, int2* __restrict__ pairs)
{
    int t = blockIdx.x * 256 + threadIdx.x;
    int g = t >> 3, sub = t & 7;
    if (g >= N_EDGES / 2) return;
    int e0 = g * 2;
    int2 ss = *(const int2*)(ei + e0);             // s0, s1
    int2 dd = *(const int2*)(ei + N_EDGES + e0);   // d0, d1

    const float4* ps0 = (const float4*)(hn + (size_t)ss.x * D);
    const float4* pd0 = (const float4*)(hn + (size_t)dd.x * D);
    const float4* ps1 = (const float4*)(hn + (size_t)ss.y * D);
    const float4* pd1 = (const float4*)(hn + (size_t)dd.y * D);
    float4 a0 = ps0[sub];
    float4 c0 = pd0[sub];
    float4 a1 = ps1[sub];
    float4 c1 = pd1[sub];

    float p0 = dot8h(a0, c0);
    float p1 = dot8h(a1, c1);
    p0 += __shfl_xor(p0, 1, 64);  p1 += __shfl_xor(p1, 1, 64);
    p0 += __shfl_xor(p0, 2, 64);  p1 += __shfl_xor(p1, 2, 64);
    p0 += __shfl_xor(p0, 4, 64);  p1 += __shfl_xor(p1, 4, 64);

    if (sub == 0) {
        float w0 = fmaxf(p0, 0.0f);
        float w1 = fmaxf(p1, 0.0f);
        *(float2*)(wout + e0) = make_float2(w0, w1);
        int2 rk = *(const int2*)(rank + e0);
        int pos0 = rowptr[dd.x] + rk.x;
        int pos1 = rowptr[dd.y] + rk.y;
        int2 pr0; pr0.x = ss.x; pr0.y = __float_as_int(w0);
        int2 pr1; pr1.x = ss.y; pr1.y = __float_as_int(w1);
        pairs[pos0] = pr0;
        pairs[pos1] = pr1;
    }
}

// ---------------------------------------------------------------------------
// deg from CSR segment-sum (coalesced); dis = rsqrt(deg) (deg>=1 always);
// y0 = dis * relu(mask)
// ---------------------------------------------------------------------------
__global__ __launch_bounds__(256) void k_dis_y(
    const int* __restrict__ rowptr, const int2* __restrict__ pairs,
    const float* __restrict__ mask, float* __restrict__ dis,
    float* __restrict__ y)
{
    int i = blockIdx.x * 256 + threadIdx.x;
    if (i >= N_NODES) return;
    int beg = rowptr[i], end = rowptr[i + 1];
    float s = 1.0f;                               // self-loop weight
    for (int j = beg; j < end; ++j)
        s += __int_as_float(pairs[j].y);
    float di = rsqrtf(fmaxf(s, EPS));
    dis[i] = di;
    y[i] = di * fmaxf(mask[i], 0.0f);
}

// ---------------------------------------------------------------------------
// APPNP step in y-domain, no atomics, raw w:
// f'_i = (1-a) * dis_i * ( sum_j w_ij*y_j + y_i ) + a*relu(mask_i)
// y'_i = dis_i * f'_i
// ---------------------------------------------------------------------------
__global__ __launch_bounds__(256) void k_spmv(
    const int* __restrict__ rowptr, const int2* __restrict__ pairs,
    const float* __restrict__ y_in, const float* __restrict__ dis,
    const float* __restrict__ mask, const float* __restrict__ alpha_p,
    float* __restrict__ y_out, float* __restrict__ f_out)
{
    int i = blockIdx.x * 256 + threadIdx.x;
    if (i >= N_NODES) return;
    int beg = rowptr[i], end = rowptr[i + 1];
    float sum = 0.0f;
    int j = beg;
    for (; j + 3 < end; j += 4) {
        int2 p0 = pairs[j];
        int2 p1 = pairs[j + 1];
        int2 p2 = pairs[j + 2];
        int2 p3 = pairs[j + 3];
        float v0 = __int_as_float(p0.y) * y_in[p0.x];
        float v1 = __int_as_float(p1.y) * y_in[p1.x];
        float v2 = __int_as_float(p2.y) * y_in[p2.x];
        float v3 = __int_as_float(p3.y) * y_in[p3.x];
        sum += (v0 + v1) + (v2 + v3);
    }
    for (; j < end; ++j) {
        int2 p = pairs[j];
        sum += __int_as_float(p.y) * y_in[p.x];
    }
    float di = dis[i];
    float alpha = alpha_p[0];
    float f0 = fmaxf(mask[i], 0.0f);
    float fn = (1.0f - alpha) * di * (sum + y_in[i]) + alpha * f0;
    f_out[i] = fn;
    y_out[i] = di * fn;
}

extern "C" void kernel_launch(void* const* d_in, const int* in_sizes, int n_in,
                              void* d_out, int out_size, void* d_ws, size_t ws_size,
                              hipStream_t stream)
{
    const float* x     = (const float*)d_in[0];
    const float* mask  = (const float*)d_in[1];
    const int*   ei    = (const int*)  d_in[2];
    const float* W     = (const float*)d_in[3];
    const float* b     = (const float*)d_in[4];
    const float* alpha = (const float*)d_in[5];

    float* out_f = (float*)d_out;
    float* out_w = (float*)d_out + N_NODES;

    // workspace layout (float-element offsets), total ~30.2 MB (<32.2 proven)
    float* ws = (float*)d_ws;
    __half* hn     = (__half*)ws;                  // 6.4M halves (3.2M floats)
    int2*  pairs   = (int2*) (ws + 3200000);       // 1.25M x 8B
    int*   rank    = (int*)  (ws + 5700000);       // 1.25M
    int*   cnt     = (int*)  (ws + 6950000);       // 100k
    int*   rowptr  = (int*)  (ws + 7050000);       // 100001 (alloc 100016)
    float* dis     =          ws + 7150016;        // 100k
    float* y_a     =          ws + 7250016;        // 100k
    float* y_b     =          ws + 7350016;        // 100k
    float* f_scr   =          ws + 7450016;        // 100k
    int*   bsum    = (int*)  (ws + 7550016);       // 391 (alloc 512)
    int*   boff    = (int*)  (ws + 7550528);       // 391

    const int nodeBlocks = (N_NODES + 255) / 256;              // 391
    const int edgeBlocks = (N_EDGES + 255) / 256;              // 4883
    const int placeBlocks = (N_EDGES / 2 * 8 + 255) / 256;     // 19532

    k_zero<<<nodeBlocks, 256, 0, stream>>>(cnt);
    k_rank<<<edgeBlocks, 256, 0, stream>>>(ei, cnt, rank);
    k_gemm_norm<<<1024, 256, 0, stream>>>(x, W, b, hn);
    k_scan1<<<nodeBlocks, 256, 0, stream>>>(cnt, rowptr, bsum);
    k_scan2<<<1, 512, 0, stream>>>(bsum, boff, nodeBlocks);
    k_scan3<<<nodeBlocks, 256, 0, stream>>>(rowptr, boff);
    k_edge_place<<<placeBlocks, 256, 0, stream>>>(hn, ei, rank, rowptr, out_w, pairs);
    k_dis_y<<<nodeBlocks, 256, 0, stream>>>(rowptr, pairs, mask, dis, y_a);

    // 5 APPNP steps in y-domain; last writes f to d_out
    k_spmv<<<nodeBlocks, 256, 0, stream>>>(rowptr, pairs, y_a, dis, mask, alpha, y_b, f_scr);
    k_spmv<<<nodeBlocks, 256, 0, stream>>>(rowptr, pairs, y_b, dis, mask, alpha, y_a, f_scr);
    k_spmv<<<nodeBlocks, 256, 0, stream>>>(rowptr, pairs, y_a, dis, mask, alpha, y_b, f_scr);
    k_spmv<<<nodeBlocks, 256, 0, stream>>>(rowptr, pairs, y_b, dis, mask, alpha, y_a, f_scr);
    k_spmv<<<nodeBlocks, 256, 0, stream>>>(rowptr, pairs, y_a, dis, mask, alpha, y_b, out_f);
}

// Round 6
// 280.870 us; speedup vs baseline: 2.3186x; 1.0100x over previous
//
#include <hip/hip_runtime.h>
#include <hip/hip_fp16.h>
#include <math.h>

#define N_NODES 100000
#define N_EDGES 1250000
#define D 64
#define EPS 1e-8f

// ---------------------------------------------------------------------------
// Kernel 1: hn[i,:] = normalize(tanh(x[i,:] @ W^T + b)) -> fp16
// ---------------------------------------------------------------------------
__global__ __launch_bounds__(256) void k_gemm_norm(
    const float* __restrict__ x, const float* __restrict__ W,
    const float* __restrict__ b, __half* __restrict__ hn)
{
    __shared__ float xrow[4][72];
    const int lane = threadIdx.x & 63;
    const int wid  = threadIdx.x >> 6;

    float Wreg[64];
    const float4* Wv = (const float4*)(W + lane * D);
    #pragma unroll
    for (int q = 0; q < 16; ++q) {
        float4 w4 = Wv[q];
        Wreg[4*q+0] = w4.x; Wreg[4*q+1] = w4.y;
        Wreg[4*q+2] = w4.z; Wreg[4*q+3] = w4.w;
    }
    const float bj = b[lane];
    float* xl = xrow[wid];

    const int wave   = blockIdx.x * 4 + wid;
    const int nwaves = gridDim.x * 4;

    for (int row = wave; row < N_NODES; row += nwaves) {
        float xv = x[(size_t)row * D + lane];
        xl[lane] = xv;
        float acc = bj;
        #pragma unroll
        for (int q = 0; q < 16; ++q) {
            float4 xk4 = *(const float4*)(xl + 4*q);
            acc = fmaf(xk4.x, Wreg[4*q+0], acc);
            acc = fmaf(xk4.y, Wreg[4*q+1], acc);
            acc = fmaf(xk4.z, Wreg[4*q+2], acc);
            acc = fmaf(xk4.w, Wreg[4*q+3], acc);
        }
        float h = tanhf(acc);
        float s = h * h;
        #pragma unroll
        for (int m = 32; m >= 1; m >>= 1) s += __shfl_xor(s, m, 64);
        float nrm = fmaxf(sqrtf(s), EPS);
        hn[(size_t)row * D + lane] = __float2half_rn(h / nrm);
    }
}

__global__ void k_zero(int* __restrict__ cnt)
{
    int i = blockIdx.x * 256 + threadIdx.x;
    if (i < N_NODES) cnt[i] = 0;
}

// ---------------------------------------------------------------------------
// The ONLY atomic pass: per-edge rank within its destination node.
// ---------------------------------------------------------------------------
__global__ void k_rank(const int* __restrict__ ei, int* __restrict__ cnt,
                       int* __restrict__ rank)
{
    int e = blockIdx.x * 256 + threadIdx.x;
    if (e >= N_EDGES) return;
    int d = ei[N_EDGES + e];
    rank[e] = atomicAdd(cnt + d, 1);
}

// ---------------------------------------------------------------------------
// Scan: exclusive prefix sum of cnt[100000] -> rowptr
// ---------------------------------------------------------------------------
__device__ __forceinline__ int wave_iscan(int v, int lane)
{
    int incl = v;
    #pragma unroll
    for (int m = 1; m < 64; m <<= 1) {
        int o = __shfl_up(incl, m, 64);
        if (lane >= m) incl += o;
    }
    return incl;
}

__global__ __launch_bounds__(256) void k_scan1(
    const int* __restrict__ cnt, int* __restrict__ rowptr, int* __restrict__ bsum)
{
    __shared__ int wsum[4];
    int t = threadIdx.x, b = blockIdx.x;
    int i = b * 256 + t;
    int lane = t & 63, wid = t >> 6;
    int v = (i < N_NODES) ? cnt[i] : 0;
    int incl = wave_iscan(v, lane);
    if (lane == 63) wsum[wid] = incl;
    __syncthreads();
    int off = 0;
    #pragma unroll
    for (int k = 0; k < 4; ++k) if (k < wid) off += wsum[k];
    if (i < N_NODES) rowptr[i] = off + incl - v;
    if (t == 255) bsum[b] = off + incl;
}

__global__ __launch_bounds__(512) void k_scan2(
    const int* __restrict__ bsum, int* __restrict__ boff, int nblk)
{
    __shared__ int wsum[8];
    int t = threadIdx.x;
    int lane = t & 63, wid = t >> 6;
    int v = (t < nblk) ? bsum[t] : 0;
    int incl = wave_iscan(v, lane);
    if (lane == 63) wsum[wid] = incl;
    __syncthreads();
    int off = 0;
    #pragma unroll
    for (int k = 0; k < 8; ++k) if (k < wid) off += wsum[k];
    if (t < nblk) boff[t] = off + incl - v;
}

__global__ __launch_bounds__(256) void k_scan3(
    int* __restrict__ rowptr, const int* __restrict__ boff)
{
    int i = blockIdx.x * 256 + threadIdx.x;
    if (i < N_NODES) rowptr[i] += boff[i >> 8];
    if (i == 0) rowptr[N_NODES] = N_EDGES;
}

// ---------------------------------------------------------------------------
// Fused cosine + CSR placement. ZERO atomics. 8 lanes/edge, 4 edges/thread
// (8 row-gathers in flight per lane).
// ---------------------------------------------------------------------------
__device__ __forceinline__ float dot8h(float4 a, float4 c)
{
    const __half2* ah = (const __half2*)&a;
    const __half2* ch = (const __half2*)&c;
    float p = 0.0f;
    #pragma unroll
    for (int q = 0; q < 4; ++q) {
        float2 af = __half22float2(ah[q]);
        float2 cf = __half22float2(ch[q]);
        p = fmaf(af.x, cf.x, p);
        p = fmaf(af.y, cf.y, p);
    }
    return p;
}

__global__ __launch_bounds__(256) void k_edge_place(
    const __half* __restrict__ hn, const int* __restrict__ ei,
    const int* __restrict__ rank, const int* __restrict__ rowptr,
    float* __restrict__ wout, int2* __restrict__ pairs)
{
    int t = blockIdx.x * 256 + threadIdx.x;
    int g = t >> 3, sub = t & 7;
    if (g >= N_EDGES / 4) return;
    int e0 = g * 4;
    int4 ss = *(const int4*)(ei + e0);
    int4 dd = *(const int4*)(ei + N_EDGES + e0);

    float4 a0 = ((const float4*)(hn + (size_t)ss.x * D))[sub];
    float4 c0 = ((const float4*)(hn + (size_t)dd.x * D))[sub];
    float4 a1 = ((const float4*)(hn + (size_t)ss.y * D))[sub];
    float4 c1 = ((const float4*)(hn + (size_t)dd.y * D))[sub];
    float4 a2 = ((const float4*)(hn + (size_t)ss.z * D))[sub];
    float4 c2 = ((const float4*)(hn + (size_t)dd.z * D))[sub];
    float4 a3 = ((const float4*)(hn + (size_t)ss.w * D))[sub];
    float4 c3 = ((const float4*)(hn + (size_t)dd.w * D))[sub];

    float p0 = dot8h(a0, c0);
    float p1 = dot8h(a1, c1);
    float p2 = dot8h(a2, c2);
    float p3 = dot8h(a3, c3);
    p0 += __shfl_xor(p0, 1, 64);  p1 += __shfl_xor(p1, 1, 64);
    p2 += __shfl_xor(p2, 1, 64);  p3 += __shfl_xor(p3, 1, 64);
    p0 += __shfl_xor(p0, 2, 64);  p1 += __shfl_xor(p1, 2, 64);
    p2 += __shfl_xor(p2, 2, 64);  p3 += __shfl_xor(p3, 2, 64);
    p0 += __shfl_xor(p0, 4, 64);  p1 += __shfl_xor(p1, 4, 64);
    p2 += __shfl_xor(p2, 4, 64);  p3 += __shfl_xor(p3, 4, 64);

    if (sub == 0) {
        float w0 = fmaxf(p0, 0.0f);
        float w1 = fmaxf(p1, 0.0f);
        float w2 = fmaxf(p2, 0.0f);
        float w3 = fmaxf(p3, 0.0f);
        *(float4*)(wout + e0) = make_float4(w0, w1, w2, w3);
        int4 rk = *(const int4*)(rank + e0);
        int pos0 = rowptr[dd.x] + rk.x;
        int pos1 = rowptr[dd.y] + rk.y;
        int pos2 = rowptr[dd.z] + rk.z;
        int pos3 = rowptr[dd.w] + rk.w;
        int2 pr;
        pr.x = ss.x; pr.y = __float_as_int(w0); pairs[pos0] = pr;
        pr.x = ss.y; pr.y = __float_as_int(w1); pairs[pos1] = pr;
        pr.x = ss.z; pr.y = __float_as_int(w2); pairs[pos2] = pr;
        pr.x = ss.w; pr.y = __float_as_int(w3); pairs[pos3] = pr;
    }
}

// ---------------------------------------------------------------------------
// deg via segment-sum, 16 lanes per node; dis = rsqrt(deg); y0 = dis*relu(mask)
// ---------------------------------------------------------------------------
__global__ __launch_bounds__(256) void k_dis_y(
    const int* __restrict__ rowptr, const int2* __restrict__ pairs,
    const float* __restrict__ mask, float* __restrict__ dis,
    float* __restrict__ y)
{
    int t = blockIdx.x * 256 + threadIdx.x;
    int node = t >> 4, l = t & 15;
    if (node >= N_NODES) return;
    int beg = rowptr[node], end = rowptr[node + 1];
    float s = 0.0f;
    for (int j = beg + l; j < end; j += 16)
        s += __int_as_float(pairs[j].y);
    s += __shfl_xor(s, 1, 64);
    s += __shfl_xor(s, 2, 64);
    s += __shfl_xor(s, 4, 64);
    s += __shfl_xor(s, 8, 64);
    if (l == 0) {
        float di = rsqrtf(fmaxf(s + 1.0f, EPS));   // +1 self-loop
        dis[node] = di;
        y[node] = di * fmaxf(mask[node], 0.0f);
    }
}

// ---------------------------------------------------------------------------
// APPNP step in y-domain, 16 lanes per node, no atomics:
// f'_i = (1-a) * dis_i * ( sum_j w_ij*y_j + y_i ) + a*relu(mask_i)
// y'_i = dis_i * f'_i
// ---------------------------------------------------------------------------
__global__ __launch_bounds__(256) void k_spmv(
    const int* __restrict__ rowptr, const int2* __restrict__ pairs,
    const float* __restrict__ y_in, const float* __restrict__ dis,
    const float* __restrict__ mask, const float* __restrict__ alpha_p,
    float* __restrict__ y_out, float* __restrict__ f_out)
{
    int t = blockIdx.x * 256 + threadIdx.x;
    int node = t >> 4, l = t & 15;
    if (node >= N_NODES) return;
    int beg = rowptr[node], end = rowptr[node + 1];
    float sum = 0.0f;
    for (int j = beg + l; j < end; j += 16) {
        int2 p = pairs[j];
        sum += __int_as_float(p.y) * y_in[p.x];
    }
    sum += __shfl_xor(sum, 1, 64);
    sum += __shfl_xor(sum, 2, 64);
    sum += __shfl_xor(sum, 4, 64);
    sum += __shfl_xor(sum, 8, 64);
    if (l == 0) {
        float di = dis[node];
        float alpha = alpha_p[0];
        float f0 = fmaxf(mask[node], 0.0f);
        float fn = (1.0f - alpha) * di * (sum + y_in[node]) + alpha * f0;
        f_out[node] = fn;
        y_out[node] = di * fn;
    }
}

extern "C" void kernel_launch(void* const* d_in, const int* in_sizes, int n_in,
                              void* d_out, int out_size, void* d_ws, size_t ws_size,
                              hipStream_t stream)
{
    const float* x     = (const float*)d_in[0];
    const float* mask  = (const float*)d_in[1];
    const int*   ei    = (const int*)  d_in[2];
    const float* W     = (const float*)d_in[3];
    const float* b     = (const float*)d_in[4];
    const float* alpha = (const float*)d_in[5];

    float* out_f = (float*)d_out;
    float* out_w = (float*)d_out + N_NODES;

    // workspace layout (float-element offsets)
    float* ws = (float*)d_ws;
    __half* hn     = (__half*)ws;                  // 6.4M halves (3.2M floats)
    int2*  pairs   = (int2*) (ws + 3200000);       // 1.25M x 8B
    int*   rank    = (int*)  (ws + 5700000);       // 1.25M
    int*   cnt     = (int*)  (ws + 6950000);       // 100k
    int*   rowptr  = (int*)  (ws + 7050000);       // 100001 (alloc 100016)
    float* dis     =          ws + 7150016;        // 100k
    float* y_a     =          ws + 7250016;        // 100k
    float* y_b     =          ws + 7350016;        // 100k
    float* f_scr   =          ws + 7450016;        // 100k
    int*   bsum    = (int*)  (ws + 7550016);       // 391 (alloc 512)
    int*   boff    = (int*)  (ws + 7550528);       // 391

    const int nodeBlocks  = (N_NODES + 255) / 256;                       // 391
    const int edgeBlocks  = (N_EDGES + 255) / 256;                       // 4883
    const int placeBlocks = (int)(((long long)(N_EDGES / 4) * 8 + 255) / 256);  // 9766
    const int segBlocks   = (int)(((long long)N_NODES * 16 + 255) / 256);       // 6250

    k_zero<<<nodeBlocks, 256, 0, stream>>>(cnt);
    k_rank<<<edgeBlocks, 256, 0, stream>>>(ei, cnt, rank);
    k_gemm_norm<<<1024, 256, 0, stream>>>(x, W, b, hn);
    k_scan1<<<nodeBlocks, 256, 0, stream>>>(cnt, rowptr, bsum);
    k_scan2<<<1, 512, 0, stream>>>(bsum, boff, nodeBlocks);
    k_scan3<<<nodeBlocks, 256, 0, stream>>>(rowptr, boff);
    k_edge_place<<<placeBlocks, 256, 0, stream>>>(hn, ei, rank, rowptr, out_w, pairs);
    k_dis_y<<<segBlocks, 256, 0, stream>>>(rowptr, pairs, mask, dis, y_a);

    // 5 APPNP steps in y-domain; last writes f to d_out
    k_spmv<<<segBlocks, 256, 0, stream>>>(rowptr, pairs, y_a, dis, mask, alpha, y_b, f_scr);
    k_spmv<<<segBlocks, 256, 0, stream>>>(rowptr, pairs, y_b, dis, mask, alpha, y_a, f_scr);
    k_spmv<<<segBlocks, 256, 0, stream>>>(rowptr, pairs, y_a, dis, mask, alpha, y_b, f_scr);
    k_spmv<<<segBlocks, 256, 0, stream>>>(rowptr, pairs, y_b, dis, mask, alpha, y_a, f_scr);
    k_spmv<<<segBlocks, 256, 0, stream>>>(rowptr, pairs, y_a, dis, mask, alpha, y_b, out_f);
}